// Round 16
// baseline (91.677 us; speedup 1.0000x reference)
//
#include <hip/hip_runtime.h>
#include <stdint.h>

#define T_STEPS 256
#define H1 5
#define H2 100
#define NSTR 16     // batch streams per block (MFMA N dim)
#define MT 7        // M tiles: 112 rows = 100 h2 + 5 h1 + 7 pad
#define ME 112
#define KE 128
#define XPAD 260    // xs row stride (floats)
#define NW 7        // one M-tile per wave; wave 6 also injects x on g3 lanes
#define NTHR (NW * 64)

typedef _Float16 f16;
typedef _Float16 half8 __attribute__((ext_vector_type(8)));
typedef _Float16 half4 __attribute__((ext_vector_type(4)));
typedef _Float16 f16x2 __attribute__((ext_vector_type(2)));
typedef float    floatx4 __attribute__((ext_vector_type(4)));

// State buffer layout (per buffer, 2048 f16 = 4 KB):
//   16B chunk (kt, g, n) at byte offset kt*1024 + g*256 + n*16
//   holds k-rows 32kt+8g .. +7 of stream n.
// K-tiles 0..2 are read as b128 (K=32 MFMA); tile 3 (rows 96..111, live
// 96..106) is read as b64 feeding a K=16 MFMA -> 56B/lane instead of 64.
// f16 index of (k, n): ((k>>5)<<9) + (((k>>3)&3)<<7) + (n<<3) + (k&7)
__device__ __forceinline__ int sidx(int k, int n) {
    return ((k >> 5) << 9) + (((k >> 3) & 3) << 7) + (n << 3) + (k & 7);
}

// tanh(x) = 1 - 2/(exp(2x)+1); saturates correctly for |x| large.
__device__ __forceinline__ float fast_tanh(float v) {
    float e = __expf(2.0f * v);
    return 1.0f - 2.0f * __builtin_amdgcn_rcpf(e + 1.0f);
}

// pack two f32 -> u32 of two f16 (RTE)
__device__ __forceinline__ uint32_t pkf16(float a, float b) {
    f16x2 v; v.x = (f16)a; v.y = (f16)b;
    return __builtin_bit_cast(uint32_t, v);
}

#define MFMA32(Aa, Bb, Dd) __builtin_amdgcn_mfma_f32_16x16x32_f16((Aa), (Bb), (Dd), 0, 0, 0)
#define MFMA16(Aa, Bb, Dd) __builtin_amdgcn_mfma_f32_16x16x16f16((Aa), (Bb), (Dd), 0, 0, 0)

// 7 waves per block, one 16-row M-tile each, 16 batch streams.
// Full 2-layer RNN step = one 112x112 fp16 matrix-vector recurrence:
//   A rows 0..99:   [Whh2 | Wih2 | bias2 | 0...]      -> h2_t
//   A rows 100..104:[  0  | Whh1 | bias1 | Wih1 | 0]  -> h1_{t+1}
// State double-buffered in LDS in B-fragment order (sidx): linear reads,
// bank-tiled writes, one barrier per step. Constants (row 105 = 1.0,
// rows 107..111 = 0) written once at init; wave 6's dead g3 lanes inject
// x_{t+2} into row 106; wave 6 g2 writes only row 104 (b16).
__global__ __launch_bounds__(NTHR, 1) void rnn_mfma7k(
    const float* __restrict__ x,
    const float* __restrict__ Wih1, const float* __restrict__ Whh1,
    const float* __restrict__ bih1, const float* __restrict__ bhh1,
    const float* __restrict__ Wih2, const float* __restrict__ Whh2,
    const float* __restrict__ bih2, const float* __restrict__ bhh2,
    const float* __restrict__ W3,   const float* __restrict__ b3,
    float* __restrict__ out)
{
    const int tid  = threadIdx.x;        // 0..447
    const int lane = tid & 63;
    const int wid  = tid >> 6;           // wave id == M-tile id
    const int n    = lane & 15;          // stream / D-col
    const int g    = lane >> 4;          // k-group / D-row-group
    const int bbase = blockIdx.x * NSTR;

    __shared__ __align__(16) f16   Wlds[ME][KE];     // 28 KB extended matrix
    __shared__ __align__(16) float xs[NSTR][XPAD];   // 16.6 KB x rows
    __shared__ __align__(16) f16   st[2][2048];      // 8 KB state (dbuf)
    __shared__ float pp[NW][NSTR];                   // epilogue partials

    // ---- zero Wlds (7168 u32 = 448*16) + preload x (1024 float4) ----
    {
        uint32_t* w32 = (uint32_t*)&Wlds[0][0];
        #pragma unroll
        for (int i = 0; i < 16; ++i) w32[tid + NTHR * i] = 0u;
        const float4* xg = (const float4*)(x + (size_t)bbase * T_STEPS);
        for (int gi = tid; gi < 1024; gi += NTHR)
            *(float4*)&xs[gi >> 6][4 * (gi & 63)] = xg[gi];
    }
    __syncthreads();
    // ---- fill extended matrix + zero state ----
    for (int i = tid; i < H2 * H2; i += NTHR) Wlds[i / H2][i % H2] = (f16)Whh2[i];
    for (int i = tid; i < H2 * H1; i += NTHR) Wlds[i / H1][H2 + i % H1] = (f16)Wih2[i];
    for (int i = tid; i < H2; i += NTHR)      Wlds[i][105] = (f16)(bih2[i] + bhh2[i]);
    if (tid < H1 * H1) Wlds[H2 + tid / H1][H2 + tid % H1] = (f16)Whh1[tid];
    if (tid < H1) {
        Wlds[H2 + tid][105] = (f16)(bih1[tid] + bhh1[tid]);
        Wlds[H2 + tid][106] = (f16)Wih1[tid];
    }
    {
        uint32_t* s32 = (uint32_t*)&st[0][0];
        for (int i = tid; i < 2048; i += NTHR) s32[i] = 0u;
    }
    __syncthreads();
    // ---- initial state: h1_0 at k=100..104 (buf0), 1 at k=105 (BOTH bufs),
    //      x_1 at k=106 (buf0). Rows 107..127 stay zero forever. ----
    if (tid < NSTR) {
        const float x0 = xs[tid][0];
        #pragma unroll
        for (int c = 0; c < H1; ++c)
            st[0][sidx(H2 + c, tid)] = (f16)fast_tanh(Wih1[c] * x0 + bih1[c] + bhh1[c]);
        st[0][sidx(105, tid)] = (f16)1.0f;
        st[1][sidx(105, tid)] = (f16)1.0f;
        st[0][sidx(106, tid)] = (f16)xs[tid][1];
    }
    // ---- A fragments for this wave's tile: 3x K32 + 1x K16 ----
    half8 Af[3];
    half4 Afk;
    #pragma unroll
    for (int kt = 0; kt < 3; ++kt)
        Af[kt] = *(const half8*)&Wlds[16 * wid + n][32 * kt + 8 * g];
    Afk = *(const half4*)&Wlds[16 * wid + n][96 + 4 * g];
    __syncthreads();

    // read bases: 3 linear b128 + 1 b64 into the tile-3 region
    const int roff   = 16 * lane;
    const int roff16 = 3072 + ((g >> 1) << 8) + (n << 4) + ((g & 1) << 3);
    // write slot: D rows 16wid+4g+{0..3}, col n
    const int woff = ((wid >> 1) << 10) + (((2 * wid + (g >> 1)) & 3) << 8)
                   + (n << 4) + ((g & 1) << 3);
    char* const sp0 = (char*)&st[0][0];
    char* const sp1 = (char*)&st[1][0];
    uint32_t P0 = 0u, P1 = 0u;

    // ---- one full step: read rp -> MFMA -> tanh -> write wp -> barrier ----
    auto fullstep = [&](const char* rp, char* wp, int t) {
        float xv = 0.0f;
        if (wid == 6) {
            const int xi = (t + 2 < T_STEPS) ? (t + 2) : (T_STEPS - 1);
            xv = xs[n][xi];
        }
        half8 Bf[3];
        #pragma unroll
        for (int kt = 0; kt < 3; ++kt)
            Bf[kt] = *(const half8*)(rp + roff + 1024 * kt);
        const half4 Bfk = *(const half4*)(rp + roff16);

        __builtin_amdgcn_s_setprio(1);
        floatx4 Da = {0.f, 0.f, 0.f, 0.f}, Db = {0.f, 0.f, 0.f, 0.f};
        Da = MFMA32(Af[0], Bf[0], Da);
        Db = MFMA32(Af[2], Bf[2], Db);
        Da = MFMA32(Af[1], Bf[1], Da);
        Db = MFMA16(Afk, Bfk, Db);
        const floatx4 D = Da + Db;

        if (wid < 6 || g < 2) {            // full uint2 write (rows all live)
            const uint32_t q0 = pkf16(fast_tanh(D[0]), fast_tanh(D[1]));
            const uint32_t q1 = pkf16(fast_tanh(D[2]), fast_tanh(D[3]));
            __builtin_amdgcn_s_setprio(0);
            uint2 w; w.x = q0; w.y = q1;
            *(uint2*)(wp + woff) = w;
        } else if (g == 2) {               // wave 6, rows 104..107: only 104 live
            const f16 h4 = (f16)fast_tanh(D[0]);
            __builtin_amdgcn_s_setprio(0);
            *(f16*)(wp + 2 * (1664 + 8 * n)) = h4;       // sidx(104,n)
        } else {                           // wave 6, g3: dead rows -> inject x
            __builtin_amdgcn_s_setprio(0);
            *(f16*)(wp + 2 * (1666 + 8 * n)) = (f16)xv;  // sidx(106,n)
        }
        __syncthreads();
    };

    #pragma unroll 1
    for (int t2 = 0; t2 < T_STEPS - 2; t2 += 2) {
        fullstep(sp0, sp1, t2);
        fullstep(sp1, sp0, t2 + 1);
    }
    fullstep(sp0, sp1, T_STEPS - 2);       // t = 254: st0 -> st1

    // ---- final step t = 255: compute only, keep P in registers ----
    {
        half8 Bf[3];
        #pragma unroll
        for (int kt = 0; kt < 3; ++kt)
            Bf[kt] = *(const half8*)(sp1 + roff + 1024 * kt);
        const half4 Bfk = *(const half4*)(sp1 + roff16);
        floatx4 Da = {0.f, 0.f, 0.f, 0.f}, Db = {0.f, 0.f, 0.f, 0.f};
        Da = MFMA32(Af[0], Bf[0], Da);
        Db = MFMA32(Af[2], Bf[2], Db);
        Da = MFMA32(Af[1], Bf[1], Da);
        Db = MFMA16(Afk, Bfk, Db);
        const floatx4 D = Da + Db;
        P0 = pkf16(fast_tanh(D[0]), fast_tanh(D[1]));
        P1 = pkf16(fast_tanh(D[2]), fast_tanh(D[3]));
    }

    // ---- epilogue: out[n] = relu(W3 . h2_255 + b3) ----
    float p = 0.0f;
    {
        const int mbase = 16 * wid + 4 * g;
        if (mbase < H2) {
            const float4 w3v = *(const float4*)(W3 + mbase);
            const f16x2 lo = __builtin_bit_cast(f16x2, P0);
            const f16x2 hi = __builtin_bit_cast(f16x2, P1);
            p += w3v.x * (float)lo.x + w3v.y * (float)lo.y
               + w3v.z * (float)hi.x + w3v.w * (float)hi.y;
        }
    }
    p += __shfl_xor(p, 16);
    p += __shfl_xor(p, 32);
    if (lane < NSTR) pp[wid][n] = p;
    __syncthreads();
    if (tid < NSTR) {
        float s = b3[0];
        #pragma unroll
        for (int w = 0; w < NW; ++w) s += pp[w][tid];
        out[bbase + tid] = fmaxf(s, 0.0f);
    }
}

extern "C" void kernel_launch(void* const* d_in, const int* in_sizes, int n_in,
                              void* d_out, int out_size, void* d_ws, size_t ws_size,
                              hipStream_t stream) {
    const float* x    = (const float*)d_in[0];
    const float* Wih1 = (const float*)d_in[1];
    const float* Whh1 = (const float*)d_in[2];
    const float* bih1 = (const float*)d_in[3];
    const float* bhh1 = (const float*)d_in[4];
    const float* Wih2 = (const float*)d_in[5];
    const float* Whh2 = (const float*)d_in[6];
    const float* bih2 = (const float*)d_in[7];
    const float* bhh2 = (const float*)d_in[8];
    const float* W3   = (const float*)d_in[9];
    const float* b3   = (const float*)d_in[10];
    float* out = (float*)d_out;

    const int B = in_sizes[0] / T_STEPS;   // 4096
    rnn_mfma7k<<<B / NSTR, NTHR, 0, stream>>>(x, Wih1, Whh1, bih1, bhh1,
                                              Wih2, Whh2, bih2, bhh2, W3, b3, out);
}

// Round 17
// 85.296 us; speedup vs baseline: 1.0748x; 1.0748x over previous
//
#include <hip/hip_runtime.h>
#include <stdint.h>

#define T_STEPS 256
#define H1 5
#define H2 100
#define NSTR 16     // batch streams per block (MFMA N dim)
#define MT 7        // M tiles: 112 rows = 100 h2 + 5 h1 + 7 pad
#define ME 112
#define KE 128
#define XPAD 260    // xs row stride (floats)
#define NW 8        // 7 compute waves (one M-tile each) + 1 light injection wave
#define NTHR (NW * 64)

typedef _Float16 f16;
typedef _Float16 half8 __attribute__((ext_vector_type(8)));
typedef _Float16 half4 __attribute__((ext_vector_type(4)));
typedef _Float16 f16x2 __attribute__((ext_vector_type(2)));
typedef float    floatx4 __attribute__((ext_vector_type(4)));

// State buffer layout (per buffer, 2048 f16 = 4 KB):
//   16B chunk (kt, g, n) at byte offset kt*1024 + g*256 + n*16
//   holds k-rows 32kt+8g .. +7 of stream n.
// K-tiles 0..2 read as b128 (K=32 MFMA); tile 3 (rows 96..111, live 96..106)
// read as b64 feeding a K=16 MFMA -> 56 B/lane instead of 64.
// f16 index of (k, n): ((k>>5)<<9) + (((k>>3)&3)<<7) + (n<<3) + (k&7)
__device__ __forceinline__ int sidx(int k, int n) {
    return ((k >> 5) << 9) + (((k >> 3) & 3) << 7) + (n << 3) + (k & 7);
}

// tanh(x) = 1 - 2/(exp(2x)+1); saturates correctly for |x| large.
__device__ __forceinline__ float fast_tanh(float v) {
    float e = __expf(2.0f * v);
    return 1.0f - 2.0f * __builtin_amdgcn_rcpf(e + 1.0f);
}

// pack two f32 -> u32 of two f16 (RTE)
__device__ __forceinline__ uint32_t pkf16(float a, float b) {
    f16x2 v; v.x = (f16)a; v.y = (f16)b;
    return __builtin_bit_cast(uint32_t, v);
}

#define MFMA32(Aa, Bb, Dd) __builtin_amdgcn_mfma_f32_16x16x32_f16((Aa), (Bb), (Dd), 0, 0, 0)
#define MFMA16(Aa, Bb, Dd) __builtin_amdgcn_mfma_f32_16x16x16f16((Aa), (Bb), (Dd), 0, 0, 0)

// 7 compute waves (one 16-row M-tile each) + 1 light wave, 16 batch streams.
// Full 2-layer RNN step = one 112x112 fp16 matrix-vector recurrence:
//   A rows 0..99:   [Whh2 | Wih2 | bias2 | 0...]      -> h2_t
//   A rows 100..104:[  0  | Whh1 | bias1 | Wih1 | 0]  -> h1_{t+1}
// State double-buffered in LDS in B-fragment order (sidx): linear reads,
// bank-tiled writes, one barrier per step.
//   - row 105 (=1.0) and rows 107..127 written ONCE at init (both bufs);
//   - wave 6 branch-free-ish: g<2 full write, g2 row-104 b16, g3 nothing;
//   - wave 7 does the x-injection (row 106) off the compute waves' path;
//   - K-tile 3 trimmed to K=16 MFMA (b64 B-read) — r16-verified mapping.
__global__ __launch_bounds__(NTHR, 1) void rnn_mfma8k(
    const float* __restrict__ x,
    const float* __restrict__ Wih1, const float* __restrict__ Whh1,
    const float* __restrict__ bih1, const float* __restrict__ bhh1,
    const float* __restrict__ Wih2, const float* __restrict__ Whh2,
    const float* __restrict__ bih2, const float* __restrict__ bhh2,
    const float* __restrict__ W3,   const float* __restrict__ b3,
    float* __restrict__ out)
{
    const int tid  = threadIdx.x;        // 0..511
    const int lane = tid & 63;
    const int wid  = tid >> 6;           // waves 0..6: M-tile id; wave 7: light
    const int n    = lane & 15;          // stream / D-col
    const int g    = lane >> 4;          // k-group / D-row-group
    const int bbase = blockIdx.x * NSTR;

    __shared__ __align__(16) f16   Wlds[ME][KE];     // 28 KB extended matrix
    __shared__ __align__(16) float xs[NSTR][XPAD];   // 16.6 KB x rows
    __shared__ __align__(16) f16   st[2][2048];      // 8 KB state (dbuf)
    __shared__ float pp[NW][NSTR];                   // epilogue partials

    // ---- zero Wlds (7168 u32 = 512*14) + preload x (1024 float4) ----
    {
        uint32_t* w32 = (uint32_t*)&Wlds[0][0];
        #pragma unroll
        for (int i = 0; i < 14; ++i) w32[tid + NTHR * i] = 0u;
        const float4* xg = (const float4*)(x + (size_t)bbase * T_STEPS);
        #pragma unroll
        for (int i = 0; i < 2; ++i) {
            const int gi = tid + NTHR * i;           // 0..1023
            *(float4*)&xs[gi >> 6][4 * (gi & 63)] = xg[gi];
        }
    }
    __syncthreads();
    // ---- fill extended matrix + zero state ----
    for (int i = tid; i < H2 * H2; i += NTHR) Wlds[i / H2][i % H2] = (f16)Whh2[i];
    for (int i = tid; i < H2 * H1; i += NTHR) Wlds[i / H1][H2 + i % H1] = (f16)Wih2[i];
    for (int i = tid; i < H2; i += NTHR)      Wlds[i][105] = (f16)(bih2[i] + bhh2[i]);
    if (tid < H1 * H1) Wlds[H2 + tid / H1][H2 + tid % H1] = (f16)Whh1[tid];
    if (tid < H1) {
        Wlds[H2 + tid][105] = (f16)(bih1[tid] + bhh1[tid]);
        Wlds[H2 + tid][106] = (f16)Wih1[tid];
    }
    {
        uint32_t* s32 = (uint32_t*)&st[0][0];
        #pragma unroll
        for (int i = 0; i < 4; ++i) s32[tid + NTHR * i] = 0u;
    }
    __syncthreads();
    // ---- initial state: h1_0 at k=100..104 (buf0), 1 at k=105 (BOTH bufs),
    //      x_1 at k=106 (buf0). Rows 107..127 stay zero forever. ----
    if (tid < NSTR) {
        const float x0 = xs[tid][0];
        #pragma unroll
        for (int c = 0; c < H1; ++c)
            st[0][sidx(H2 + c, tid)] = (f16)fast_tanh(Wih1[c] * x0 + bih1[c] + bhh1[c]);
        st[0][sidx(105, tid)] = (f16)1.0f;
        st[1][sidx(105, tid)] = (f16)1.0f;
        st[0][sidx(106, tid)] = (f16)xs[tid][1];
    }
    // ---- A fragments (compute waves only): 3x K32 + 1x K16 ----
    half8 Af[3];
    half4 Afk = {0, 0, 0, 0};
    if (wid < MT) {
        #pragma unroll
        for (int kt = 0; kt < 3; ++kt)
            Af[kt] = *(const half8*)&Wlds[16 * wid + n][32 * kt + 8 * g];
        Afk = *(const half4*)&Wlds[16 * wid + n][96 + 4 * g];
    }
    __syncthreads();

    // read bases: 3 linear b128 + 1 b64 into the tile-3 region
    const int roff   = 16 * lane;
    const int roff16 = 3072 + ((g >> 1) << 8) + (n << 4) + ((g & 1) << 3);
    // write slot: D rows 16wid+4g+{0..3}, col n
    const int woff = ((wid >> 1) << 10) + (((2 * wid + (g >> 1)) & 3) << 8)
                   + (n << 4) + ((g & 1) << 3);
    char* const sp0 = (char*)&st[0][0];
    char* const sp1 = (char*)&st[1][0];
    uint32_t P0 = 0u, P1 = 0u;

    if (wid == 7) {
        // ---- light wave: per-step x-injection into row 106 of the next buf ----
        f16* const w0 = &st[0][0];
        f16* const w1 = &st[1][0];
        const int si = sidx(106, n);
        #pragma unroll 1
        for (int t2 = 0; t2 < T_STEPS - 2; t2 += 2) {
            if (lane < NSTR) w1[si] = (f16)xs[n][t2 + 2];
            __syncthreads();
            if (lane < NSTR) w0[si] = (f16)xs[n][t2 + 3 < T_STEPS ? t2 + 3 : T_STEPS - 1];
            __syncthreads();
        }
        if (lane < NSTR) w1[si] = (f16)xs[n][T_STEPS - 1];   // t = 254 (clamped)
        __syncthreads();
        // final step: nothing to do
    } else {
        // ---- compute waves: one full step = read rp -> MFMA -> tanh -> write wp ----
        auto fullstep = [&](const char* rp, char* wp) {
            half8 Bf[3];
            #pragma unroll
            for (int kt = 0; kt < 3; ++kt)
                Bf[kt] = *(const half8*)(rp + roff + 1024 * kt);
            const half4 Bfk = *(const half4*)(rp + roff16);

            __builtin_amdgcn_s_setprio(1);
            floatx4 Da = {0.f, 0.f, 0.f, 0.f}, Db = {0.f, 0.f, 0.f, 0.f};
            Da = MFMA32(Af[0], Bf[0], Da);
            Db = MFMA32(Af[2], Bf[2], Db);
            Da = MFMA32(Af[1], Bf[1], Da);
            Db = MFMA16(Afk, Bfk, Db);
            const floatx4 D = Da + Db;

            if (wid < 6 || g < 2) {        // full uint2 write (rows all live)
                const uint32_t q0 = pkf16(fast_tanh(D[0]), fast_tanh(D[1]));
                const uint32_t q1 = pkf16(fast_tanh(D[2]), fast_tanh(D[3]));
                __builtin_amdgcn_s_setprio(0);
                uint2 w; w.x = q0; w.y = q1;
                *(uint2*)(wp + woff) = w;
            } else if (g == 2) {           // wave 6, rows 104..107: only 104 live
                const f16 h4 = (f16)fast_tanh(D[0]);
                __builtin_amdgcn_s_setprio(0);
                *(f16*)(wp + 2 * (1664 + 8 * n)) = h4;   // sidx(104,n)*2 bytes
            } else {                       // wave 6, g == 3: rows 108..111 dead
                __builtin_amdgcn_s_setprio(0);
            }
            __syncthreads();
        };

        #pragma unroll 1
        for (int t2 = 0; t2 < T_STEPS - 2; t2 += 2) {
            fullstep(sp0, sp1);
            fullstep(sp1, sp0);
        }
        fullstep(sp0, sp1);                // t = 254: st0 -> st1

        // ---- final step t = 255: compute only, keep P in registers ----
        half8 Bf[3];
        #pragma unroll
        for (int kt = 0; kt < 3; ++kt)
            Bf[kt] = *(const half8*)(sp1 + roff + 1024 * kt);
        const half4 Bfk = *(const half4*)(sp1 + roff16);
        floatx4 Da = {0.f, 0.f, 0.f, 0.f}, Db = {0.f, 0.f, 0.f, 0.f};
        Da = MFMA32(Af[0], Bf[0], Da);
        Db = MFMA32(Af[2], Bf[2], Db);
        Da = MFMA32(Af[1], Bf[1], Da);
        Db = MFMA16(Afk, Bfk, Db);
        const floatx4 D = Da + Db;
        P0 = pkf16(fast_tanh(D[0]), fast_tanh(D[1]));
        P1 = pkf16(fast_tanh(D[2]), fast_tanh(D[3]));
    }

    // ---- epilogue: out[n] = relu(W3 . h2_255 + b3) ----
    float p = 0.0f;
    if (wid < MT) {
        const int mbase = 16 * wid + 4 * g;
        if (mbase < H2) {
            const float4 w3v = *(const float4*)(W3 + mbase);
            const f16x2 lo = __builtin_bit_cast(f16x2, P0);
            const f16x2 hi = __builtin_bit_cast(f16x2, P1);
            p += w3v.x * (float)lo.x + w3v.y * (float)lo.y
               + w3v.z * (float)hi.x + w3v.w * (float)hi.y;
        }
    }
    p += __shfl_xor(p, 16);
    p += __shfl_xor(p, 32);
    if (lane < NSTR) pp[wid][n] = p;
    __syncthreads();
    if (tid < NSTR) {
        float s = b3[0];
        #pragma unroll
        for (int w = 0; w < MT; ++w) s += pp[w][tid];
        out[bbase + tid] = fmaxf(s, 0.0f);
    }
}

extern "C" void kernel_launch(void* const* d_in, const int* in_sizes, int n_in,
                              void* d_out, int out_size, void* d_ws, size_t ws_size,
                              hipStream_t stream) {
    const float* x    = (const float*)d_in[0];
    const float* Wih1 = (const float*)d_in[1];
    const float* Whh1 = (const float*)d_in[2];
    const float* bih1 = (const float*)d_in[3];
    const float* bhh1 = (const float*)d_in[4];
    const float* Wih2 = (const float*)d_in[5];
    const float* Whh2 = (const float*)d_in[6];
    const float* bih2 = (const float*)d_in[7];
    const float* bhh2 = (const float*)d_in[8];
    const float* W3   = (const float*)d_in[9];
    const float* b3   = (const float*)d_in[10];
    float* out = (float*)d_out;

    const int B = in_sizes[0] / T_STEPS;   // 4096
    rnn_mfma8k<<<B / NSTR, NTHR, 0, stream>>>(x, Wih1, Whh1, bih1, bhh1,
                                              Wih2, Whh2, bih2, bhh2, W3, b3, out);
}

// Round 18
// 83.873 us; speedup vs baseline: 1.0931x; 1.0170x over previous
//
#include <hip/hip_runtime.h>
#include <stdint.h>

#define T_STEPS 256
#define H1 5
#define H2 100
#define NSTR 16     // batch streams per block (MFMA N dim)
#define MT 7        // M tiles: 112 rows = 100 h2 + 5 h1 + 7 pad
#define KT 4        // K tiles: 128 cols = 100 h2 + 5 h1 + bias + x + 21 pad
#define ME 112
#define KE 128
#define XPAD 260    // xs row stride (floats)
#define NW 8        // 7 compute waves (one M-tile each) + 1 light injection wave
#define NTHR (NW * 64)

typedef _Float16 f16;
typedef _Float16 half8 __attribute__((ext_vector_type(8)));
typedef _Float16 f16x2 __attribute__((ext_vector_type(2)));
typedef float    floatx4 __attribute__((ext_vector_type(4)));

// State buffer layout (per buffer, 2048 f16 = 4 KB):
//   16B chunk (kt, g, n) at byte offset kt*1024 + g*256 + n*16
//   holds k-rows 32kt+8g .. +7 of stream n.
// B-read for lane l=(g*16+n): addr = lane*16 + kt*1024  -> perfectly linear.
// f16 index of (k, n): ((k>>5)<<9) + (((k>>3)&3)<<7) + (n<<3) + (k&7)
__device__ __forceinline__ int sidx(int k, int n) {
    return ((k >> 5) << 9) + (((k >> 3) & 3) << 7) + (n << 3) + (k & 7);
}

// tanh(x) = 1 - 2/(exp(2x)+1); saturates correctly for |x| large.
__device__ __forceinline__ float fast_tanh(float v) {
    float e = __expf(2.0f * v);
    return 1.0f - 2.0f * __builtin_amdgcn_rcpf(e + 1.0f);
}

// pack two f32 -> u32 of two f16 (RTE)
__device__ __forceinline__ uint32_t pkf16(float a, float b) {
    f16x2 v; v.x = (f16)a; v.y = (f16)b;
    return __builtin_bit_cast(uint32_t, v);
}

// 7 compute waves (one 16-row M-tile each) + 1 light wave, 16 batch streams.
// Full 2-layer RNN step = one 112x128 fp16 matrix-vector recurrence:
//   A rows 0..99:   [Whh2 | Wih2 | bias2 | 0...]      -> h2_t
//   A rows 100..104:[  0  | Whh1 | bias1 | Wih1 | 0]  -> h1_{t+1}
// State double-buffered in LDS in B-fragment order (sidx): linear reads,
// bank-tiled writes, one barrier per step.
//   - row 105 (=1.0) and rows 107..127 written ONCE at init (both bufs);
//   - wave 6 branch-light in the loop (g2 writes only row 104 via b16);
//   - wave 7 does the x-injection (row 106) off the compute waves' path.
// This configuration measured 83.9 us (round 14) and survived 7 structural
// perturbations (rounds 12,13,15,16,17) all null or negative — it is the
// empirical optimum of the barrier-synced MFMA recurrence family.
__global__ __launch_bounds__(NTHR, 1) void rnn_mfma8(
    const float* __restrict__ x,
    const float* __restrict__ Wih1, const float* __restrict__ Whh1,
    const float* __restrict__ bih1, const float* __restrict__ bhh1,
    const float* __restrict__ Wih2, const float* __restrict__ Whh2,
    const float* __restrict__ bih2, const float* __restrict__ bhh2,
    const float* __restrict__ W3,   const float* __restrict__ b3,
    float* __restrict__ out)
{
    const int tid  = threadIdx.x;        // 0..511
    const int lane = tid & 63;
    const int wid  = tid >> 6;           // waves 0..6: M-tile id; wave 7: light
    const int n    = lane & 15;          // stream / D-col
    const int g    = lane >> 4;          // k-group / D-row-group
    const int bbase = blockIdx.x * NSTR;

    __shared__ __align__(16) f16   Wlds[ME][KE];     // 28 KB extended matrix
    __shared__ __align__(16) float xs[NSTR][XPAD];   // 16.6 KB x rows
    __shared__ __align__(16) f16   st[2][2048];      // 8 KB state (dbuf)
    __shared__ float pp[NW][NSTR];                   // epilogue partials

    // ---- zero Wlds (7168 u32 = 512*14) + preload x (1024 float4) ----
    {
        uint32_t* w32 = (uint32_t*)&Wlds[0][0];
        #pragma unroll
        for (int i = 0; i < 14; ++i) w32[tid + NTHR * i] = 0u;
        const float4* xg = (const float4*)(x + (size_t)bbase * T_STEPS);
        #pragma unroll
        for (int i = 0; i < 2; ++i) {
            const int gi = tid + NTHR * i;           // 0..1023
            *(float4*)&xs[gi >> 6][4 * (gi & 63)] = xg[gi];
        }
    }
    __syncthreads();
    // ---- fill extended matrix + zero state ----
    for (int i = tid; i < H2 * H2; i += NTHR) Wlds[i / H2][i % H2] = (f16)Whh2[i];
    for (int i = tid; i < H2 * H1; i += NTHR) Wlds[i / H1][H2 + i % H1] = (f16)Wih2[i];
    for (int i = tid; i < H2; i += NTHR)      Wlds[i][105] = (f16)(bih2[i] + bhh2[i]);
    if (tid < H1 * H1) Wlds[H2 + tid / H1][H2 + tid % H1] = (f16)Whh1[tid];
    if (tid < H1) {
        Wlds[H2 + tid][105] = (f16)(bih1[tid] + bhh1[tid]);
        Wlds[H2 + tid][106] = (f16)Wih1[tid];
    }
    {
        uint32_t* s32 = (uint32_t*)&st[0][0];
        #pragma unroll
        for (int i = 0; i < 4; ++i) s32[tid + NTHR * i] = 0u;
    }
    __syncthreads();
    // ---- initial state: h1_0 at k=100..104 (buf0), 1 at k=105 (BOTH bufs),
    //      x_1 at k=106 (buf0). Rows 107..127 stay zero forever. ----
    if (tid < NSTR) {
        const float x0 = xs[tid][0];
        #pragma unroll
        for (int c = 0; c < H1; ++c)
            st[0][sidx(H2 + c, tid)] = (f16)fast_tanh(Wih1[c] * x0 + bih1[c] + bhh1[c]);
        st[0][sidx(105, tid)] = (f16)1.0f;
        st[1][sidx(105, tid)] = (f16)1.0f;
        st[0][sidx(106, tid)] = (f16)xs[tid][1];
    }
    // ---- A fragments (compute waves only; wave 7 has no rows) ----
    half8 Af[KT];
    if (wid < MT) {
        #pragma unroll
        for (int kt = 0; kt < KT; ++kt)
            Af[kt] = *(const half8*)&Wlds[16 * wid + n][32 * kt + 8 * g];
    }
    __syncthreads();

    // read base: linear per lane; write slot: D rows 16wid+4g+{0..3}, col n
    const int roff = 16 * lane;
    const int woff = ((wid >> 1) << 10) + (((2 * wid + (g >> 1)) & 3) << 8)
                   + (n << 4) + ((g & 1) << 3);
    char* const sp0 = (char*)&st[0][0];
    char* const sp1 = (char*)&st[1][0];
    uint32_t P0 = 0u, P1 = 0u;

    if (wid == 7) {
        // ---- light wave: per-step x-injection into row 106 of the next buf ----
        f16* const w0 = &st[0][0];
        f16* const w1 = &st[1][0];
        const int si = sidx(106, n);
        #pragma unroll 1
        for (int t2 = 0; t2 < T_STEPS - 2; t2 += 2) {
            if (lane < NSTR) w1[si] = (f16)xs[n][t2 + 2];
            __syncthreads();
            if (lane < NSTR) w0[si] = (f16)xs[n][t2 + 3 < T_STEPS ? t2 + 3 : T_STEPS - 1];
            __syncthreads();
        }
        if (lane < NSTR) w1[si] = (f16)xs[n][T_STEPS - 1];   // t = 254 (clamped)
        __syncthreads();
        // final step: nothing to do
    } else {
        // ---- compute waves: one full step = read rp -> MFMA -> tanh -> write wp ----
        auto fullstep = [&](const char* rp, char* wp) {
            half8 Bf[KT];
            #pragma unroll
            for (int kt = 0; kt < KT; ++kt)
                Bf[kt] = *(const half8*)(rp + roff + 1024 * kt);

            __builtin_amdgcn_s_setprio(1);
            floatx4 Da = {0.f, 0.f, 0.f, 0.f}, Db = {0.f, 0.f, 0.f, 0.f};
            Da = __builtin_amdgcn_mfma_f32_16x16x32_f16(Af[0], Bf[0], Da, 0, 0, 0);
            Db = __builtin_amdgcn_mfma_f32_16x16x32_f16(Af[2], Bf[2], Db, 0, 0, 0);
            Da = __builtin_amdgcn_mfma_f32_16x16x32_f16(Af[1], Bf[1], Da, 0, 0, 0);
            Db = __builtin_amdgcn_mfma_f32_16x16x32_f16(Af[3], Bf[3], Db, 0, 0, 0);
            const floatx4 D = Da + Db;

            if (wid < 6 || g < 2) {        // full uint2 write (rows all live)
                const uint32_t q0 = pkf16(fast_tanh(D[0]), fast_tanh(D[1]));
                const uint32_t q1 = pkf16(fast_tanh(D[2]), fast_tanh(D[3]));
                __builtin_amdgcn_s_setprio(0);
                uint2 w; w.x = q0; w.y = q1;
                *(uint2*)(wp + woff) = w;
            } else if (g == 2) {           // wave 6, rows 104..107: only 104 live
                const f16 h4 = (f16)fast_tanh(D[0]);
                __builtin_amdgcn_s_setprio(0);
                *(f16*)(wp + 2 * (1664 + 8 * n)) = h4;   // sidx(104,n)*2 bytes
            } else {                       // wave 6, g == 3: rows 108..111 dead
                __builtin_amdgcn_s_setprio(0);
            }
            __syncthreads();
        };

        #pragma unroll 1
        for (int t2 = 0; t2 < T_STEPS - 2; t2 += 2) {
            fullstep(sp0, sp1);
            fullstep(sp1, sp0);
        }
        fullstep(sp0, sp1);                // t = 254: st0 -> st1

        // ---- final step t = 255: compute only, keep P in registers ----
        half8 Bf[KT];
        #pragma unroll
        for (int kt = 0; kt < KT; ++kt)
            Bf[kt] = *(const half8*)(sp1 + roff + 1024 * kt);
        floatx4 Da = {0.f, 0.f, 0.f, 0.f}, Db = {0.f, 0.f, 0.f, 0.f};
        Da = __builtin_amdgcn_mfma_f32_16x16x32_f16(Af[0], Bf[0], Da, 0, 0, 0);
        Db = __builtin_amdgcn_mfma_f32_16x16x32_f16(Af[2], Bf[2], Db, 0, 0, 0);
        Da = __builtin_amdgcn_mfma_f32_16x16x32_f16(Af[1], Bf[1], Da, 0, 0, 0);
        Db = __builtin_amdgcn_mfma_f32_16x16x32_f16(Af[3], Bf[3], Db, 0, 0, 0);
        const floatx4 D = Da + Db;
        P0 = pkf16(fast_tanh(D[0]), fast_tanh(D[1]));
        P1 = pkf16(fast_tanh(D[2]), fast_tanh(D[3]));
    }

    // ---- epilogue: out[n] = relu(W3 . h2_255 + b3) ----
    float p = 0.0f;
    if (wid < MT) {
        const int mbase = 16 * wid + 4 * g;
        if (mbase < H2) {
            const float4 w3v = *(const float4*)(W3 + mbase);
            const f16x2 lo = __builtin_bit_cast(f16x2, P0);
            const f16x2 hi = __builtin_bit_cast(f16x2, P1);
            p += w3v.x * (float)lo.x + w3v.y * (float)lo.y
               + w3v.z * (float)hi.x + w3v.w * (float)hi.y;
        }
    }
    p += __shfl_xor(p, 16);
    p += __shfl_xor(p, 32);
    if (lane < NSTR) pp[wid][n] = p;
    __syncthreads();
    if (tid < NSTR) {
        float s = b3[0];
        #pragma unroll
        for (int w = 0; w < MT; ++w) s += pp[w][tid];
        out[bbase + tid] = fmaxf(s, 0.0f);
    }
}

extern "C" void kernel_launch(void* const* d_in, const int* in_sizes, int n_in,
                              void* d_out, int out_size, void* d_ws, size_t ws_size,
                              hipStream_t stream) {
    const float* x    = (const float*)d_in[0];
    const float* Wih1 = (const float*)d_in[1];
    const float* Whh1 = (const float*)d_in[2];
    const float* bih1 = (const float*)d_in[3];
    const float* bhh1 = (const float*)d_in[4];
    const float* Wih2 = (const float*)d_in[5];
    const float* Whh2 = (const float*)d_in[6];
    const float* bih2 = (const float*)d_in[7];
    const float* bhh2 = (const float*)d_in[8];
    const float* W3   = (const float*)d_in[9];
    const float* b3   = (const float*)d_in[10];
    float* out = (float*)d_out;

    const int B = in_sizes[0] / T_STEPS;   // 4096
    rnn_mfma8<<<B / NSTR, NTHR, 0, stream>>>(x, Wih1, Whh1, bih1, bhh1,
                                             Wih2, Whh2, bih2, bhh2, W3, b3, out);
}